// Round 4
// baseline (172.005 us; speedup 1.0000x reference)
//
#include <hip/hip_runtime.h>
#include <hip/hip_bf16.h>

#define B_ 32
#define T_ 2048
#define D_ 1024
#define A_ 128

typedef __attribute__((ext_vector_type(8))) short bf16x8;
typedef __attribute__((ext_vector_type(4))) float f32x4;

static __device__ __forceinline__ unsigned short f2bf(float f) {
  union { float f; unsigned u; } v; v.f = f;
  unsigned r = v.u + 0x7FFFu + ((v.u >> 16) & 1u);
  return (unsigned short)(r >> 16);
}

// packed f32x2 -> bf16x2 (RNE); compiler emits v_cvt_pk_bf16_f32
static __device__ __forceinline__ unsigned cvt2u(float lo, float hi) {
  __hip_bfloat162 h2 = __float22bfloat162_rn(make_float2(lo, hi));
  unsigned u;
  __builtin_memcpy(&u, &h2, 4);
  return u;
}

// barrier that only drains LDS ops; register-destined global loads stay in flight
static __device__ __forceinline__ void barrier_lds() {
  asm volatile("s_waitcnt lgkmcnt(0)\n\ts_barrier" ::: "memory");
}

// ---------------- prep: Wt[a][d] = bf16(Ws[d][a]) ----------------
__global__ __launch_bounds__(256) void k_prep(const float* __restrict__ Ws,
                                              unsigned short* __restrict__ Wt) {
  int i = blockIdx.x * 256 + threadIdx.x;  // coalesced write
  int a = i >> 10, d = i & 1023;
  Wt[i] = f2bf(Ws[(size_t)d * A_ + a]);
}

// ---------------- fused: scores -> exp -> weighted x accumulation ----------------
// grid (8, 32): blockIdx.x = t-slice (256 t), blockIdx.y = b. 512 thr (8 waves), 1 blk/CU.
// Counted-vmcnt pipeline: loads for chunk i+2 issued during chunk i; lgkm-only barriers
// (no vmcnt(0) drain in the loop). x accumulated from registers in exact f32.
#define LDRB 1032  // bf16 row stride in shorts (2064 B)
#define LDRF 1028  // f32 row stride for final reduce (4112 B)

__global__ __launch_bounds__(512, 2) void k_fused(const float* __restrict__ x,
                                                  const unsigned short* __restrict__ Wt,
                                                  const float* __restrict__ bs,
                                                  const float* __restrict__ us,
                                                  float* __restrict__ part,
                                                  float* __restrict__ Zp) {
  __shared__ __align__(16) char smem[16 * LDRF * 4];  // 65,792 B: ab (33 KB) ⊂ red space
  __shared__ float sc_part[16 * 8];
  unsigned short* ab = (unsigned short*)smem;  // bf16 A-buffer [16][LDRB]
  float* red = (float*)smem;                   // final reduce  [16][LDRF]

  const int tid  = threadIdx.x;
  const int w    = tid >> 6;
  const int lane = tid & 63;
  const int lrow = lane & 15;
  const int g    = lane >> 4;
  const int sub  = blockIdx.x;
  const int b    = blockIdx.y;

  // W^T fragments for this wave's 16 a-columns, register-resident (128 VGPR)
  const int a_col = w * 16 + lrow;
  bf16x8 wreg[32];
  {
    const unsigned short* wr = Wt + (size_t)a_col * D_ + g * 8;
#pragma unroll
    for (int kt = 0; kt < 32; ++kt) wreg[kt] = *(const bf16x8*)(wr + kt * 32);
  }
  const float bsv = bs[a_col];
  const float usv = us[a_col];

  // staging: thread owns row srow (one t of 16), 8 contiguous f32 at scol + q*256
  const int srow = w * 2 + (lane >> 5);
  const int scol = (lane & 31) * 8;
  const float* gx = x + ((size_t)b * T_ + (size_t)sub * 256) * D_;

#define ISSUE(dst, ci)                                                            \
  {                                                                               \
    const float* gp_ = gx + (size_t)(ci) * 16 * D_ + (size_t)srow * D_ + scol;    \
    _Pragma("unroll") for (int q = 0; q < 4; ++q) {                               \
      dst[2 * q]     = *(const float4*)(gp_ + q * 256);                           \
      dst[2 * q + 1] = *(const float4*)(gp_ + q * 256 + 4);                       \
    }                                                                             \
  }

#define WRITE_AB(src)                                                             \
  {                                                                               \
    _Pragma("unroll") for (int q = 0; q < 4; ++q) {                               \
      uint4 h_;                                                                   \
      h_.x = cvt2u(src[2 * q].x, src[2 * q].y);                                   \
      h_.y = cvt2u(src[2 * q].z, src[2 * q].w);                                   \
      h_.z = cvt2u(src[2 * q + 1].x, src[2 * q + 1].y);                           \
      h_.w = cvt2u(src[2 * q + 1].z, src[2 * q + 1].w);                           \
      *(uint4*)(&ab[srow * LDRB + scol + q * 256]) = h_;                          \
    }                                                                             \
  }

// GEMM z[16t][16a] over K=1024 from ab; then e = exp(score) for this thread's row.
// C layout: col = lane&15 (a), row = g*4 + r (t). |score| <= ||us||_1 ~ 9 => exp safe.
#define SCORE_TO_E(e_out)                                                         \
  {                                                                               \
    f32x4 accm = (f32x4)0.f;                                                      \
    const unsigned short* arow = ab + lrow * LDRB + g * 8;                        \
    _Pragma("unroll") for (int kt = 0; kt < 32; ++kt) {                           \
      bf16x8 af = *(const bf16x8*)(arow + kt * 32);                               \
      accm = __builtin_amdgcn_mfma_f32_16x16x32_bf16(af, wreg[kt], accm, 0, 0, 0);\
    }                                                                             \
    _Pragma("unroll") for (int r = 0; r < 4; ++r) {                               \
      float p = usv * tanhf(accm[r] + bsv);                                       \
      _Pragma("unroll") for (int o = 1; o < 16; o <<= 1) p += __shfl_xor(p, o, 64);\
      if (lrow == 0) sc_part[(g * 4 + r) * 8 + w] = p;                            \
    }                                                                             \
    barrier_lds();                                                                \
    const float4 p0 = *(const float4*)(sc_part + srow * 8);                       \
    const float4 p1 = *(const float4*)(sc_part + srow * 8 + 4);                   \
    e_out = expf(p0.x + p0.y + p0.z + p0.w + p1.x + p1.y + p1.z + p1.w);          \
  }

  float4 stA[8], stB[8];
  f32x4 acc[8];
#pragma unroll
  for (int j = 0; j < 8; ++j) acc[j] = (f32x4)0.f;
  float zacc = 0.f;

  // prologue: chunks 0,1 in flight; write chunk 0's bf16 (compiler waits vmcnt(8))
  ISSUE(stA, 0);
  ISSUE(stB, 1);
  __builtin_amdgcn_sched_barrier(0);
  WRITE_AB(stA);
  barrier_lds();

  for (int i = 0; i < 16; i += 2) {
    // -------- phase A: chunk i (data in stA, ab holds chunk i) --------
    {
      float e;
      SCORE_TO_E(e);
      zacc += e;
#pragma unroll
      for (int j = 0; j < 8; ++j) {
        acc[j][0] = fmaf(e, stA[j].x, acc[j][0]);
        acc[j][1] = fmaf(e, stA[j].y, acc[j][1]);
        acc[j][2] = fmaf(e, stA[j].z, acc[j][2]);
        acc[j][3] = fmaf(e, stA[j].w, acc[j][3]);
      }
      if (i < 14) ISSUE(stA, i + 2);          // chunk i+2 into freed stA
      __builtin_amdgcn_sched_barrier(0);
      WRITE_AB(stB);                          // chunk i+1 (vmcnt counted, i+2 in flight)
      barrier_lds();
    }
    // -------- phase B: chunk i+1 (data in stB, ab holds chunk i+1) --------
    {
      float e;
      SCORE_TO_E(e);
      zacc += e;
#pragma unroll
      for (int j = 0; j < 8; ++j) {
        acc[j][0] = fmaf(e, stB[j].x, acc[j][0]);
        acc[j][1] = fmaf(e, stB[j].y, acc[j][1]);
        acc[j][2] = fmaf(e, stB[j].z, acc[j][2]);
        acc[j][3] = fmaf(e, stB[j].w, acc[j][3]);
      }
      if (i + 3 < 16) ISSUE(stB, i + 3);      // chunk i+3 into freed stB
      __builtin_amdgcn_sched_barrier(0);
      if (i < 14) WRITE_AB(stA);              // chunk i+2
      barrier_lds();
    }
  }

  // -------- epilogue: combine 16 row-owners per d through LDS (one-time) --------
  // zacc is identical across the 32 lanes sharing srow; one writer per row.
  if ((lane & 31) == 0) sc_part[srow] = zacc;
#pragma unroll
  for (int q = 0; q < 4; ++q) {
    *(f32x4*)(&red[srow * LDRF + scol + q * 256])     = acc[2 * q];
    *(f32x4*)(&red[srow * LDRF + scol + q * 256 + 4]) = acc[2 * q + 1];
  }
  barrier_lds();

  float s0 = 0.f, s1 = 0.f;
#pragma unroll
  for (int r = 0; r < 16; ++r) {
    const float2 v = *(const float2*)(&red[r * LDRF + tid * 2]);
    s0 += v.x;
    s1 += v.y;
  }
  *(float2*)(part + ((size_t)sub * B_ + b) * D_ + tid * 2) = make_float2(s0, s1);
  if (tid == 0) {
    float Z = 0.f;
#pragma unroll
    for (int r = 0; r < 16; ++r) Z += sc_part[r];
    Zp[b * 8 + sub] = Z;
  }
#undef ISSUE
#undef WRITE_AB
#undef SCORE_TO_E
}

// ---------------- reduce 8 slice-partials, divide by Z ----------------
__global__ __launch_bounds__(256) void k_reduce(const float* __restrict__ part,
                                                const float* __restrict__ Zp,
                                                float* __restrict__ out) {
  const int i = blockIdx.x * 256 + threadIdx.x;  // 0..32767
  const int b = i >> 10, d = i & 1023;
  float zs = 0.f;
#pragma unroll
  for (int s = 0; s < 8; ++s) zs += Zp[b * 8 + s];
  float acc = 0.f;
#pragma unroll
  for (int s = 0; s < 8; ++s) acc += part[((size_t)s * B_ + b) * D_ + d];
  out[i] = acc / zs;
}

extern "C" void kernel_launch(void* const* d_in, const int* in_sizes, int n_in,
                              void* d_out, int out_size, void* d_ws, size_t ws_size,
                              hipStream_t stream) {
  const float* x  = (const float*)d_in[0];
  const float* Ws = (const float*)d_in[1];
  const float* bs = (const float*)d_in[2];
  const float* us = (const float*)d_in[3];
  float* out = (float*)d_out;

  char* ws = (char*)d_ws;
  unsigned short* Wt = (unsigned short*)ws;                 // 256 KB
  float* part = (float*)(ws + (256 << 10));                 // 1 MB
  float* Zp   = (float*)(ws + (256 << 10) + (1 << 20));     // 1 KB

  k_prep<<<512, 256, 0, stream>>>(Ws, Wt);
  k_fused<<<dim3(8, B_), 512, 0, stream>>>(x, Wt, bs, us, part, Zp);
  k_reduce<<<(B_ * D_) / 256, 256, 0, stream>>>(part, Zp, out);
}

// Round 5
// 73.303 us; speedup vs baseline: 2.3465x; 2.3465x over previous
//
#include <hip/hip_runtime.h>
#include <hip/hip_bf16.h>

#define B_ 32
#define T_ 2048
#define D_ 1024
#define A_ 128

typedef __attribute__((ext_vector_type(8))) short bf16x8;
typedef __attribute__((ext_vector_type(4))) float f32x4;

static __device__ __forceinline__ unsigned short f2bf(float f) {
  union { float f; unsigned u; } v; v.f = f;
  unsigned r = v.u + 0x7FFFu + ((v.u >> 16) & 1u);
  return (unsigned short)(r >> 16);
}

// packed f32x2 -> bf16x2 (RNE); compiler emits v_cvt_pk_bf16_f32
static __device__ __forceinline__ unsigned cvt2u(float lo, float hi) {
  __hip_bfloat162 h2 = __float22bfloat162_rn(make_float2(lo, hi));
  unsigned u;
  __builtin_memcpy(&u, &h2, 4);
  return u;
}

// barrier that only drains LDS ops (keeps prefetch global loads in flight)
static __device__ __forceinline__ void barrier_lds() {
  asm volatile("s_waitcnt lgkmcnt(0)\n\ts_barrier" ::: "memory");
}

// ---------------- prep: Wt[a][d] = bf16(Ws[d][a]) ----------------
__global__ __launch_bounds__(256) void k_prep(const float* __restrict__ Ws,
                                              unsigned short* __restrict__ Wt) {
  int i = blockIdx.x * 256 + threadIdx.x;  // coalesced write
  int a = i >> 10, d = i & 1023;
  Wt[i] = f2bf(Ws[(size_t)d * A_ + a]);
}

// ---------------- fused: scores -> exp -> weighted x accumulation ----------------
// grid (8, 32): blockIdx.x = t-slice (256 t), blockIdx.y = b. 512 thr (8 waves), 1 blk/CU.
// NOTE: no min-occupancy arg in __launch_bounds__ — (512,2) empirically caps VGPR at 128
// and this kernel needs ~190 (wreg alone = 128); the cap caused scratch spills (r4:
// FETCH +149 MB, WRITE +37 MB). Grid == CU count, so >1 block/CU is unreachable anyway.
#define LDRF 1028  // f32 row stride (4112 B): +16B pad, conflict-free b128/b64
#define LDRB 1032  // bf16 row stride in shorts (2064 B): +16B pad

__global__ __launch_bounds__(512) void k_fused(const float* __restrict__ x,
                                               const unsigned short* __restrict__ Wt,
                                               const float* __restrict__ bs,
                                               const float* __restrict__ us,
                                               float* __restrict__ part,
                                               float* __restrict__ Zp) {
  __shared__ __align__(16) float xb[16 * LDRF];            // 65,792 B (exact f32 chunk)
  __shared__ __align__(16) unsigned short ab[16 * LDRB];   // 33,024 B (bf16 A-buffer)
  __shared__ float sc_part[16 * 8];
  __shared__ float e_lds[16];

  const int tid  = threadIdx.x;
  const int w    = tid >> 6;
  const int lane = tid & 63;
  const int lrow = lane & 15;
  const int g    = lane >> 4;
  const int sub  = blockIdx.x;
  const int b    = blockIdx.y;

  // W^T fragments for this wave's 16 a-columns, register-resident (128 VGPR)
  const int a_col = w * 16 + lrow;
  bf16x8 wreg[32];
  {
    const unsigned short* wr = Wt + (size_t)a_col * D_ + g * 8;
#pragma unroll
    for (int kt = 0; kt < 32; ++kt) wreg[kt] = *(const bf16x8*)(wr + kt * 32);
  }
  const float bsv = bs[a_col];
  const float usv = us[a_col];

  // staging: row srow (0..15), cols scol+q*128, q=0..7 (coalesced 512B/seg)
  const int srow = w * 2 + (lane >> 5);
  const int scol = (lane & 31) * 4;
  const float* gx = x + ((size_t)b * T_ + (size_t)sub * 256) * D_;

  float4 st[8];
  // prologue: chunk 0 -> regs -> LDS (f32 + bf16)
#pragma unroll
  for (int q = 0; q < 8; ++q)
    st[q] = *(const float4*)(gx + (size_t)srow * D_ + scol + q * 128);
#pragma unroll
  for (int q = 0; q < 8; ++q) {
    *(float4*)(&xb[srow * LDRF + scol + q * 128]) = st[q];
    unsigned lo = cvt2u(st[q].x, st[q].y);
    unsigned hi = cvt2u(st[q].z, st[q].w);
    *(uint2*)(&ab[srow * LDRB + scol + q * 128]) = make_uint2(lo, hi);
  }
  __syncthreads();

  float a0 = 0.f, a1 = 0.f, zacc = 0.f;

  for (int i = 0; i < 16; ++i) {
    // issue next-chunk global loads NOW; they land during this chunk's compute
    if (i < 15) {
      const float* gc = gx + (size_t)(i + 1) * 16 * D_;
#pragma unroll
      for (int q = 0; q < 8; ++q)
        st[q] = *(const float4*)(gc + (size_t)srow * D_ + scol + q * 128);
    }
    __builtin_amdgcn_sched_barrier(0);  // pin load issue above the compute

    // GEMM: z[16 t][16 a-cols of this wave] over K=1024, A-frags bf16 from ab
    f32x4 accm = (f32x4)0.f;
    const unsigned short* arow = ab + lrow * LDRB + g * 8;
#pragma unroll
    for (int kt = 0; kt < 32; ++kt) {
      bf16x8 af = *(const bf16x8*)(arow + kt * 32);
      accm = __builtin_amdgcn_mfma_f32_16x16x32_bf16(af, wreg[kt], accm, 0, 0, 0);
    }

    // per-wave score partial: sum over this wave's 16 a of us*tanh(z+bs)
    // C layout: col = lane&15 (a), row = g*4 + r (t)
#pragma unroll
    for (int r = 0; r < 4; ++r) {
      float p = usv * tanhf(accm[r] + bsv);
#pragma unroll
      for (int o = 1; o < 16; o <<= 1) p += __shfl_xor(p, o, 64);
      if (lrow == 0) sc_part[(g * 4 + r) * 8 + w] = p;
    }
    barrier_lds();

    // |score| <= ||us||_1 ~ 9 => exp without max-shift is safe in f32
    if (tid < 16) {
      float s = 0.f;
#pragma unroll
      for (int ww = 0; ww < 8; ++ww) s += sc_part[tid * 8 + ww];
      e_lds[tid] = expf(s);
    }
    barrier_lds();

    // exact f32 accumulate: thread owns d = 2*tid, 2*tid+1
    const float* xd = xb + tid * 2;
#pragma unroll
    for (int t = 0; t < 16; ++t) {
      const float2 v = *(const float2*)(xd + t * LDRF);
      const float ev = e_lds[t];
      a0 = fmaf(ev, v.x, a0);
      a1 = fmaf(ev, v.y, a1);
      zacc += ev;  // uniform across threads; thread 0 writes
    }
    __syncthreads();  // chunk i fully consumed (also waits staged loads)

    if (i < 15) {
      // write staged regs: f32 copy + bf16 copy (converted once per element)
#pragma unroll
      for (int q = 0; q < 8; ++q) {
        *(float4*)(&xb[srow * LDRF + scol + q * 128]) = st[q];
        unsigned lo = cvt2u(st[q].x, st[q].y);
        unsigned hi = cvt2u(st[q].z, st[q].w);
        *(uint2*)(&ab[srow * LDRB + scol + q * 128]) = make_uint2(lo, hi);
      }
      __syncthreads();
    }
  }

  float* pp = part + ((size_t)sub * B_ + b) * D_ + tid * 2;
  *(float2*)pp = make_float2(a0, a1);
  if (tid == 0) Zp[b * 8 + sub] = zacc;
}

// ---------------- reduce 8 slice-partials, divide by Z ----------------
__global__ __launch_bounds__(256) void k_reduce(const float* __restrict__ part,
                                                const float* __restrict__ Zp,
                                                float* __restrict__ out) {
  const int i = blockIdx.x * 256 + threadIdx.x;  // 0..32767
  const int b = i >> 10, d = i & 1023;
  float zs = 0.f;
#pragma unroll
  for (int s = 0; s < 8; ++s) zs += Zp[b * 8 + s];
  float acc = 0.f;
#pragma unroll
  for (int s = 0; s < 8; ++s) acc += part[((size_t)s * B_ + b) * D_ + d];
  out[i] = acc / zs;
}

extern "C" void kernel_launch(void* const* d_in, const int* in_sizes, int n_in,
                              void* d_out, int out_size, void* d_ws, size_t ws_size,
                              hipStream_t stream) {
  const float* x  = (const float*)d_in[0];
  const float* Ws = (const float*)d_in[1];
  const float* bs = (const float*)d_in[2];
  const float* us = (const float*)d_in[3];
  float* out = (float*)d_out;

  char* ws = (char*)d_ws;
  unsigned short* Wt = (unsigned short*)ws;                 // 256 KB
  float* part = (float*)(ws + (256 << 10));                 // 1 MB
  float* Zp   = (float*)(ws + (256 << 10) + (1 << 20));     // 1 KB

  k_prep<<<512, 256, 0, stream>>>(Ws, Wt);
  k_fused<<<dim3(8, B_), 512, 0, stream>>>(x, Wt, bs, us, part, Zp);
  k_reduce<<<(B_ * D_) / 256, 256, 0, stream>>>(part, Zp, out);
}